// Round 4
// baseline (321.412 us; speedup 1.0000x reference)
//
#include <hip/hip_runtime.h>
#include <stdint.h>

// Problem constants (fixed by setup_inputs: 4096x4096 f32, block_size=128)
#define RR 4096
#define CC 4096
#define BS 128
#define NB 32              // CC / BS column blocks
#define K1 262143u         // lower median rank (0-indexed) of N = RR*BS = 524288
//
// Semantics target: float64 ground truth (harness "ref=np" recomputes in f64).
//   score64 = ((f64)w * (f64)w) / ((f64)d * (f64)d)   -- squares exact, one rounded div
//   thr = f64 linear-interp quantile(0.5) lies strictly in (v1,v2) (or == v1 on exact tie)
//   => mask == (score64 <= v1_64). Nonnegative f64 orders identically to its u64 bits,
//   so we radix-select the rank-K1 64-bit key per column block and compare keys.

// ws layout:
//   [0, 32K)                 : dd64[4096] double  (d*d per column, exact)
//   [32K, 32K + 6*256K)      : hist[6][32][2048] u32   (per-pass regions, one memset)
//   then                     : prefix64[32] u64 | krem[32] u32

__global__ void diag_k(const float* __restrict__ H, double* __restrict__ dd) {
    int c = blockIdx.x * 256 + threadIdx.x;
    if (c < CC) {
        double d = (double)H[(size_t)c * CC + c];
        dd[c] = d * d;
    }
}

__device__ __forceinline__ uint64_t sbits(float w, double dd) {
    double s = ((double)w * (double)w) / dd;
    return (uint64_t)__double_as_longlong(s);
}

// Each wg: one 64-row x 128-col tile of one column block.
template <int SHIFT, int BITS, bool FIRST>
__global__ void hist_k(const float* __restrict__ Wt, const double* __restrict__ dd,
                       const uint64_t* __restrict__ prefix, uint32_t* __restrict__ hist) {
    const int b = blockIdx.y;       // column block 0..31
    const int w = blockIdx.x;       // row tile   0..63
    const int tid = threadIdx.x;    // 0..255
    const int NBIN = 1 << BITS;
    __shared__ uint32_t lh[1 << BITS];
    for (int i = tid; i < NBIN; i += 256) lh[i] = 0;
    __syncthreads();

    uint64_t pfx = 0;
    if (!FIRST) pfx = prefix[b];

    const float4* W4 = (const float4*)Wt;

    // tile = 64 rows x 32 float4 cols -> 2048 float4s, 8 iters of 256 threads
#pragma unroll
    for (int it = 0; it < 8; ++it) {
        int e = it * 256 + tid;
        int c4 = e & 31;
        int rl = e >> 5;
        size_t row = (size_t)(w * 64 + rl);
        float4 wv = W4[row * (CC / 4) + b * (BS / 4) + c4];
        int cb = b * BS + c4 * 4;
        uint64_t u[4];
        u[0] = sbits(wv.x, dd[cb + 0]);
        u[1] = sbits(wv.y, dd[cb + 1]);
        u[2] = sbits(wv.z, dd[cb + 2]);
        u[3] = sbits(wv.w, dd[cb + 3]);
#pragma unroll
        for (int j = 0; j < 4; ++j) {
            if (FIRST) {
                atomicAdd(&lh[(uint32_t)(u[j] >> SHIFT) & (uint32_t)(NBIN - 1)], 1u);
            } else {
                if ((u[j] >> (SHIFT + BITS)) == pfx)
                    atomicAdd(&lh[(uint32_t)(u[j] >> SHIFT) & (uint32_t)(NBIN - 1)], 1u);
            }
        }
    }
    __syncthreads();
    for (int i = tid; i < NBIN; i += 256) {
        uint32_t v = lh[i];
        if (v) atomicAdd(&hist[b * NBIN + i], v);
    }
}

template <int BITS, bool FIRST>
__global__ void select_k(const uint32_t* __restrict__ hist, uint64_t* prefix, uint32_t* krem) {
    const int b = blockIdx.x;
    const int tid = threadIdx.x;
    const int NBIN = 1 << BITS;
    const int PER = NBIN / 256;   // 8 (11-bit) or 4 (10-bit)
    __shared__ uint32_t part[256];
    uint32_t s = 0;
    for (int j = 0; j < PER; ++j) s += hist[b * NBIN + tid * PER + j];
    part[tid] = s;
    __syncthreads();
    if (tid == 0) {
        uint32_t k = FIRST ? K1 : krem[b];
        uint32_t cum = 0;
        int t = 0;
        while (t < 255 && cum + part[t] <= k) { cum += part[t]; ++t; }
        int bin = t * PER;
        while (cum + hist[b * NBIN + bin] <= k) { cum += hist[b * NBIN + bin]; ++bin; }
        krem[b] = k - cum;                      // rank within selected class
        prefix[b] = FIRST ? (uint64_t)bin : ((prefix[b] << BITS) | (uint64_t)bin);
    }
}

__global__ void mask_k(const float* __restrict__ Wt, const double* __restrict__ dd,
                       const uint64_t* __restrict__ key1, int* __restrict__ out) {
    size_t e4 = (size_t)blockIdx.x * 256 + threadIdx.x;  // float4 index, total RR*CC/4
    const float4* W4 = (const float4*)Wt;
    int4* O4 = (int4*)out;
    int c4 = (int)(e4 & (CC / 4 - 1));  // 0..1023 within-row float4 col
    int b = c4 >> 5;                    // column block
    float4 wv = W4[e4];
    int cb = c4 * 4;
    uint64_t kk = key1[b];
    int4 o;
    o.x = (sbits(wv.x, dd[cb + 0]) <= kk) ? 1 : 0;
    o.y = (sbits(wv.y, dd[cb + 1]) <= kk) ? 1 : 0;
    o.z = (sbits(wv.z, dd[cb + 2]) <= kk) ? 1 : 0;
    o.w = (sbits(wv.w, dd[cb + 3]) <= kk) ? 1 : 0;
    O4[e4] = o;
}

extern "C" void kernel_launch(void* const* d_in, const int* in_sizes, int n_in,
                              void* d_out, int out_size, void* d_ws, size_t ws_size,
                              hipStream_t stream) {
    const float* Wt = (const float*)d_in[0];
    const float* H  = (const float*)d_in[1];
    int* out = (int*)d_out;

    char* ws = (char*)d_ws;
    double* dd = (double*)ws;                                  // 32 KB
    uint32_t* histbase = (uint32_t*)(ws + 32768);              // 6 x 256 KB
    const size_t HREG = (size_t)NB * 2048;                     // u32s per region
    uint64_t* prefix = (uint64_t*)(ws + 32768 + 6 * HREG * 4); // 32 x u64
    uint32_t* krem   = (uint32_t*)((char*)prefix + NB * 8);    // 32 x u32

    diag_k<<<dim3((CC + 255) / 256), dim3(256), 0, stream>>>(H, dd);
    hipMemsetAsync(histbase, 0, 6 * HREG * 4, stream);

    dim3 hg(64, NB), hb(256);

    hist_k<53, 11, true ><<<hg, hb, 0, stream>>>(Wt, dd, prefix, histbase + 0 * HREG);
    select_k<11, true ><<<dim3(NB), dim3(256), 0, stream>>>(histbase + 0 * HREG, prefix, krem);

    hist_k<42, 11, false><<<hg, hb, 0, stream>>>(Wt, dd, prefix, histbase + 1 * HREG);
    select_k<11, false><<<dim3(NB), dim3(256), 0, stream>>>(histbase + 1 * HREG, prefix, krem);

    hist_k<31, 11, false><<<hg, hb, 0, stream>>>(Wt, dd, prefix, histbase + 2 * HREG);
    select_k<11, false><<<dim3(NB), dim3(256), 0, stream>>>(histbase + 2 * HREG, prefix, krem);

    hist_k<20, 11, false><<<hg, hb, 0, stream>>>(Wt, dd, prefix, histbase + 3 * HREG);
    select_k<11, false><<<dim3(NB), dim3(256), 0, stream>>>(histbase + 3 * HREG, prefix, krem);

    hist_k<10, 10, false><<<hg, hb, 0, stream>>>(Wt, dd, prefix, histbase + 4 * HREG);
    select_k<10, false><<<dim3(NB), dim3(256), 0, stream>>>(histbase + 4 * HREG, prefix, krem);

    hist_k< 0, 10, false><<<hg, hb, 0, stream>>>(Wt, dd, prefix, histbase + 5 * HREG);
    select_k<10, false><<<dim3(NB), dim3(256), 0, stream>>>(histbase + 5 * HREG, prefix, krem);

    // prefix[b] now holds the full 64-bit key of the rank-K1 (v1) score.
    mask_k<<<dim3(RR * CC / 4 / 256), dim3(256), 0, stream>>>(Wt, dd, prefix, out);
}

// Round 5
// 233.492 us; speedup vs baseline: 1.3765x; 1.3765x over previous
//
#include <hip/hip_runtime.h>
#include <stdint.h>

// Problem constants (fixed by setup_inputs: 4096x4096 f32, block_size=128)
#define RR 4096
#define CC 4096
#define BS 128
#define NB 32              // CC / BS column blocks
#define K1 262143u         // lower median rank (0-indexed) of N = RR*BS = 524288
#define CAP 8192           // max candidates per block in the 22-bit-prefix class
//
// Semantics (verified round 4, absmax 0): f64 ground truth.
//   score64 = ((f64)w*(f64)w) / ((f64)d*(f64)d); mask = (score64 <= v1_64),
//   v1 = rank-K1 order statistic per column block. Nonneg f64 orders as u64 bits.
// This version computes keys ONCE: store khi = key>>32 (64MB, L3-resident),
// radix-select 11+11 bits on khi, compact the ~200-candidate 22-bit class,
// finish exactly on recomputed full keys, mask from khi (+rare exact recheck).

__device__ __forceinline__ uint64_t sbits(float w, double dd) {
    double s = ((double)w * (double)w) / dd;
    return (uint64_t)__double_as_longlong(s);
}

__global__ void diag_k(const float* __restrict__ H, double* __restrict__ dd) {
    int c = blockIdx.x * 256 + threadIdx.x;
    if (c < CC) {
        double d = (double)H[(size_t)c * CC + c];
        dd[c] = d * d;
    }
}

// Full W scan: compute khi, write it, LDS-histogram top 11 bits (key bits 53..63).
__global__ void pass1_k(const float* __restrict__ Wt, const double* __restrict__ dd,
                        uint32_t* __restrict__ khi, uint32_t* __restrict__ hist) {
    const int b = blockIdx.y, w = blockIdx.x, tid = threadIdx.x;
    __shared__ uint32_t lh[2048];
    __shared__ double ldd[BS];
    for (int i = tid; i < 2048; i += 256) lh[i] = 0;
    if (tid < BS) ldd[tid] = dd[b * BS + tid];
    __syncthreads();

    const float4* W4 = (const float4*)Wt;
    uint4* K4 = (uint4*)khi;
#pragma unroll
    for (int it = 0; it < 8; ++it) {
        int e = it * 256 + tid;
        int c4 = e & 31;
        int rl = e >> 5;
        size_t row = (size_t)(w * 64 + rl);
        size_t idx4 = row * (CC / 4) + b * (BS / 4) + c4;
        float4 wv = W4[idx4];
        int cl = c4 * 4;
        uint4 kh;
        kh.x = (uint32_t)(sbits(wv.x, ldd[cl + 0]) >> 32);
        kh.y = (uint32_t)(sbits(wv.y, ldd[cl + 1]) >> 32);
        kh.z = (uint32_t)(sbits(wv.z, ldd[cl + 2]) >> 32);
        kh.w = (uint32_t)(sbits(wv.w, ldd[cl + 3]) >> 32);
        K4[idx4] = kh;
        atomicAdd(&lh[kh.x >> 21], 1u);
        atomicAdd(&lh[kh.y >> 21], 1u);
        atomicAdd(&lh[kh.z >> 21], 1u);
        atomicAdd(&lh[kh.w >> 21], 1u);
    }
    __syncthreads();
    for (int i = tid; i < 2048; i += 256) {
        uint32_t v = lh[i];
        if (v) atomicAdd(&hist[b * 2048 + i], v);
    }
}

// khi scan: histogram khi bits 10..20 among elements matching the 11-bit prefix.
__global__ void pass2_k(const uint32_t* __restrict__ khi, const uint32_t* __restrict__ prefix,
                        uint32_t* __restrict__ hist) {
    const int b = blockIdx.y, w = blockIdx.x, tid = threadIdx.x;
    __shared__ uint32_t lh[2048];
    for (int i = tid; i < 2048; i += 256) lh[i] = 0;
    __syncthreads();
    const uint32_t pfx = prefix[b];
    const uint4* K4 = (const uint4*)khi;
#pragma unroll
    for (int it = 0; it < 8; ++it) {
        int e = it * 256 + tid;
        int c4 = e & 31;
        int rl = e >> 5;
        size_t row = (size_t)(w * 64 + rl);
        uint4 kh = K4[row * (CC / 4) + b * (BS / 4) + c4];
        if ((kh.x >> 21) == pfx) atomicAdd(&lh[(kh.x >> 10) & 2047u], 1u);
        if ((kh.y >> 21) == pfx) atomicAdd(&lh[(kh.y >> 10) & 2047u], 1u);
        if ((kh.z >> 21) == pfx) atomicAdd(&lh[(kh.z >> 10) & 2047u], 1u);
        if ((kh.w >> 21) == pfx) atomicAdd(&lh[(kh.w >> 10) & 2047u], 1u);
    }
    __syncthreads();
    for (int i = tid; i < 2048; i += 256) {
        uint32_t v = lh[i];
        if (v) atomicAdd(&hist[b * 2048 + i], v);
    }
}

template <bool FIRST>
__global__ void select_k(const uint32_t* __restrict__ hist, uint32_t* prefix, uint32_t* krem) {
    const int b = blockIdx.x;
    const int tid = threadIdx.x;
    __shared__ uint32_t part[256];
    uint32_t s = 0;
    for (int j = 0; j < 8; ++j) s += hist[b * 2048 + tid * 8 + j];
    part[tid] = s;
    __syncthreads();
    if (tid == 0) {
        uint32_t k = FIRST ? K1 : krem[b];
        uint32_t cum = 0;
        int t = 0;
        while (t < 255 && cum + part[t] <= k) { cum += part[t]; ++t; }
        int bin = t * 8;
        while (cum + hist[b * 2048 + bin] <= k) { cum += hist[b * 2048 + bin]; ++bin; }
        krem[b] = k - cum;
        prefix[b] = FIRST ? (uint32_t)bin : ((prefix[b] << 11) | (uint32_t)bin);
    }
}

// khi scan: compact flat indices of all elements in the selected 22-bit class.
__global__ void compact_k(const uint32_t* __restrict__ khi, const uint32_t* __restrict__ prefix,
                          uint32_t* __restrict__ cnt, uint32_t* __restrict__ cand) {
    const int b = blockIdx.y, w = blockIdx.x, tid = threadIdx.x;
    const uint32_t pfx = prefix[b];
    const uint4* K4 = (const uint4*)khi;
#pragma unroll
    for (int it = 0; it < 8; ++it) {
        int e = it * 256 + tid;
        int c4 = e & 31;
        int rl = e >> 5;
        size_t row = (size_t)(w * 64 + rl);
        size_t idx4 = row * (CC / 4) + b * (BS / 4) + c4;
        uint4 kh = K4[idx4];
        uint32_t base = (uint32_t)(idx4 * 4);
#pragma unroll
        for (int j = 0; j < 4; ++j) {
            uint32_t k = (j == 0) ? kh.x : (j == 1) ? kh.y : (j == 2) ? kh.z : kh.w;
            if ((k >> 10) == pfx) {
                uint32_t p = atomicAdd(&cnt[b], 1u);
                if (p < CAP) cand[(size_t)b * CAP + p] = base + j;
            }
        }
    }
}

// Per block: recompute exact f64 keys for candidates, select rank krem exactly.
__global__ void final_k(const float* __restrict__ Wt, const double* __restrict__ dd,
                        const uint32_t* __restrict__ cnt, const uint32_t* __restrict__ cand,
                        const uint32_t* __restrict__ krem, uint64_t* __restrict__ key1) {
    const int b = blockIdx.x;
    const int tid = threadIdx.x;
    __shared__ uint64_t keys[CAP];   // 64 KB
    int n = (int)min(cnt[b], (uint32_t)CAP);
    for (int j = tid; j < n; j += 256) {
        uint32_t idx = cand[(size_t)b * CAP + j];
        keys[j] = sbits(Wt[idx], dd[idx & (CC - 1)]);
    }
    __syncthreads();
    uint32_t k = krem[b];
    for (int j = tid; j < n; j += 256) {
        uint64_t kj = keys[j];
        uint32_t cl = 0, ce = 0;
        for (int i = 0; i < n; ++i) {
            uint64_t ki = keys[i];
            cl += (ki < kj);
            ce += (ki == kj);
        }
        if (cl <= k && k < cl + ce) key1[b] = kj;  // unique satisfying value
    }
}

__global__ void mask_k(const float* __restrict__ Wt, const double* __restrict__ dd,
                       const uint32_t* __restrict__ khi, const uint64_t* __restrict__ key1,
                       int* __restrict__ out) {
    size_t e4 = (size_t)blockIdx.x * 256 + threadIdx.x;  // uint4 index
    const uint4* K4 = (const uint4*)khi;
    int4* O4 = (int4*)out;
    int c4 = (int)(e4 & (CC / 4 - 1));
    int b = c4 >> 5;
    uint64_t k1 = key1[b];
    uint32_t khi1 = (uint32_t)(k1 >> 32);
    uint4 kh = K4[e4];
    size_t base = e4 * 4;
    int4 o;
    o.x = (kh.x != khi1) ? (kh.x < khi1) : (sbits(Wt[base + 0], dd[(base + 0) & (CC - 1)]) <= k1);
    o.y = (kh.y != khi1) ? (kh.y < khi1) : (sbits(Wt[base + 1], dd[(base + 1) & (CC - 1)]) <= k1);
    o.z = (kh.z != khi1) ? (kh.z < khi1) : (sbits(Wt[base + 2], dd[(base + 2) & (CC - 1)]) <= k1);
    o.w = (kh.w != khi1) ? (kh.w < khi1) : (sbits(Wt[base + 3], dd[(base + 3) & (CC - 1)]) <= k1);
    O4[e4] = o;
}

extern "C" void kernel_launch(void* const* d_in, const int* in_sizes, int n_in,
                              void* d_out, int out_size, void* d_ws, size_t ws_size,
                              hipStream_t stream) {
    const float* Wt = (const float*)d_in[0];
    const float* H  = (const float*)d_in[1];
    int* out = (int*)d_out;

    char* ws = (char*)d_ws;
    // layout:
    //   [0, 32K)            dd[4096] f64
    //   [32K, 288K)         hist1[32][2048] u32   \  one memset covers
    //   [288K, 544K)        hist2[32][2048] u32    } hist1+hist2+cnt
    //   [544K, 544K+128)    cnt[32] u32           /
    //   [560K, ...)         prefix[32] u32 | krem[32] u32 | key1[32] u64
    //   [1M, 65M)           khi[4096*4096] u32
    //   [65M+1M=66M window) cand[32][CAP] u32 (1MB) placed at 66M
    double*   dd    = (double*)ws;
    uint32_t* hist1 = (uint32_t*)(ws + (32u << 10));
    uint32_t* hist2 = (uint32_t*)(ws + (288u << 10));
    uint32_t* cnt   = (uint32_t*)(ws + (544u << 10));
    uint32_t* prefix= (uint32_t*)(ws + (560u << 10));
    uint32_t* krem  = prefix + 32;
    uint64_t* key1  = (uint64_t*)(prefix + 64);
    uint32_t* khi   = (uint32_t*)(ws + (1u << 20));
    uint32_t* cand  = (uint32_t*)(ws + (66u << 20));

    diag_k<<<dim3((CC + 255) / 256), dim3(256), 0, stream>>>(H, dd);
    // zero hist1 + hist2 + cnt in one shot: [32K, 544K+128)
    hipMemsetAsync(ws + (32u << 10), 0, (512u << 10) + 128, stream);

    dim3 hg(64, NB), hb(256);
    pass1_k<<<hg, hb, 0, stream>>>(Wt, dd, khi, hist1);
    select_k<true ><<<dim3(NB), dim3(256), 0, stream>>>(hist1, prefix, krem);

    pass2_k<<<hg, hb, 0, stream>>>(khi, prefix, hist2);
    select_k<false><<<dim3(NB), dim3(256), 0, stream>>>(hist2, prefix, krem);

    compact_k<<<hg, hb, 0, stream>>>(khi, prefix, cnt, cand);
    final_k<<<dim3(NB), dim3(256), 0, stream>>>(Wt, dd, cnt, cand, krem, key1);

    mask_k<<<dim3(RR * CC / 4 / 256), dim3(256), 0, stream>>>(Wt, dd, khi, key1, out);
}